// Round 1
// baseline (313.460 us; speedup 1.0000x reference)
//
#include <hip/hip_runtime.h>
#include <math.h>

#ifndef M_PI
#define M_PI 3.14159265358979323846
#endif

// Problem constants
#define HH 192
#define WW 192
#define CC 16
#define FF 32
#define BB 8
#define NBI 68        // active frequency box per spatial axis (freqs -34..33)
#define ROW0 62       // first centered (pre-fftshift) row of the mask box
#define MASK_T 4560   // (2i-191)^2 + (2j-191)^2 <= 4560  <=>  d/dmax < 0.25 (exact)
#define NWC (WW*CC)   // 3072
#define SCALE (1.0f/1179648.0f)   // 1/(192*192*32) ifft normalization

// Workspace layout (bytes). Lifetime-packed; peak need = 55,152,640 B.
#define OFF_TAB  0ull
#define OFF_JMIN 1536ull
#define OFF_RST  1824ull
#define OFF_KQ   4096ull        // 68*68*16*32 float2 = 18,939,904 -> ends 18,944,000
#define OFF_T1   18944000ull    // 8*68*192*16 float2 = 13,369,344 -> ends 32,313,344
#define OFF_T2   32313344ull    // 8*68*68*16 float2  =  4,734,976 -> ends 37,048,320
#define OFF_M2   18944000ull    // reuses T1 (dead after k_dft_w);   9,469,952 -> ends 28,413,952
#define OFF_M3   28413952ull    // 8*68*192*32 float2 = 26,738,688 -> ends 55,152,640 (T2 dead)

__device__ __forceinline__ float2 cmul(float2 a, float2 b) {
    return make_float2(a.x*b.x - a.y*b.y, a.x*b.y + a.y*b.x);
}

// K0: 192-root twiddle table (double-precision build) + mask row tables.
__global__ __launch_bounds__(192) void k_tables(float2* __restrict__ tab,
                                                int* __restrict__ jmin,
                                                int* __restrict__ rstart) {
    int t = threadIdx.x;
    if (t < 192) {
        double th = (2.0 * M_PI / 192.0) * (double)t;
        double s, c;
        sincos(th, &s, &c);
        tab[t] = make_float2((float)c, (float)s);   // e^{+2pi i t/192}
    }
    __shared__ int cnt_s[NBI], jmn_s[NBI];
    if (t < NBI) {
        int ii = ROW0 + t;
        int a = 2*ii - 191;
        int rem = MASK_T - a*a;           // always >= 0 for rows 62..129
        int q = (int)sqrtf((float)rem);
        while ((q+1)*(q+1) <= rem) q++;
        while (q > 0 && q*q > rem) q--;
        jmn_s[t] = (192 - q) >> 1;                        // ceil((191-q)/2)
        cnt_s[t] = ((191 + q) >> 1) - ((192 - q) >> 1) + 1;
    }
    __syncthreads();
    if (t == 0) {
        int acc = 0;
        for (int i = 0; i < NBI; i++) {
            rstart[i] = acc;
            acc += cnt_s[i];
            jmin[i] = jmn_s[i];
        }
        // acc == 3576 (= N_ACTIVE / (C*F)), verified analytically.
    }
}

// K1: scatter the flat weights into the 68x68 box AND fold in the C-forward-DFT
// and F-inverse-DFT:  KQ[c',g] = sum_{c,f} e^{-2pi i c c'/16} K[c,f] e^{+2pi i f g/32}
__global__ __launch_bounds__(256) void k_densify(
        const float* __restrict__ kr, const float* __restrict__ ki,
        const float2* __restrict__ tab, const int* __restrict__ jmin,
        const int* __restrict__ rstart, float2* __restrict__ KQ) {
    int blk = blockIdx.x;                 // bi*68 + bj
    int bi = blk / NBI, bj = blk - bi*NBI;
    int tid = threadIdx.x;
    float2* KQo = KQ + (size_t)blk * (CC*FF);
    int a = 2*(ROW0+bi) - 191;
    int bc = 2*(ROW0+bj) - 191;
    bool masked = (a*a + bc*bc) <= MASK_T;   // block-uniform
    if (!masked) {
        for (int e = tid; e < CC*FF; e += 256) KQo[e] = make_float2(0.f, 0.f);
        return;
    }
    __shared__ float2 Kc[CC][FF+1];
    __shared__ float2 Kt[CC][FF+1];
    __shared__ float2 tl[192];
    for (int e = tid; e < 192; e += 256) tl[e] = tab[e];
    int rank = rstart[bi] + ((ROW0+bj) - jmin[bi]);
    size_t base = (size_t)rank * (CC*FF);
    for (int e = tid; e < CC*FF; e += 256)
        Kc[e>>5][e&31] = make_float2(kr[base+e], ki[base+e]);
    __syncthreads();
    for (int e = tid; e < CC*FF; e += 256) {      // Kt[cp][f] = DFT16_c
        int cp = e >> 5, f = e & 31;
        float2 acc = make_float2(0.f, 0.f);
        #pragma unroll
        for (int c = 0; c < CC; c++) {
            int tt = (12*c*cp) % 192;             // 2pi/16 = 2pi*12/192
            float2 w = tl[tt];
            float2 v = Kc[c][f];
            acc.x += v.x*w.x + v.y*w.y;           // v * conj(w)
            acc.y += v.y*w.x - v.x*w.y;
        }
        Kt[cp][f] = acc;
    }
    __syncthreads();
    for (int e = tid; e < CC*FF; e += 256) {      // KQ[cp][g] = iDFT32_f
        int cp = e >> 5, g = e & 31;
        float2 acc = make_float2(0.f, 0.f);
        #pragma unroll
        for (int f = 0; f < FF; f++) {
            int tt = (6*f*g) % 192;               // 2pi/32 = 2pi*6/192
            float2 w = tl[tt];
            float2 v = Kt[cp][f];
            acc.x += v.x*w.x - v.y*w.y;           // v * w
            acc.y += v.x*w.y + v.y*w.x;
        }
        KQo[cp*FF + g] = acc;
    }
}

// K_A: partial forward DFT over H at the 68 active freqs (rotation twiddles).
// T1[b][bi][w][c] = sum_h in[b][h][w][c] * e^{-2pi i s_i h/192},  s_i = bi-34
__global__ __launch_bounds__(256) void k_dft_h(
        const float* __restrict__ in, const float2* __restrict__ tab,
        float2* __restrict__ T1) {
    int bg = blockIdx.x;          // 0..16, 4 bi each
    int b  = blockIdx.y;
    int z  = blockIdx.z;          // wc quarter
    int tid = threadIdx.x;
    const float* inb = in + (size_t)b * HH * NWC;
    int wc0 = z * 768 + tid;
    float2 tw[4], r[4];
    #pragma unroll
    for (int u = 0; u < 4; u++) {
        int s = bg*4 + u - 34;
        int ts = ((s % 192) + 192) % 192;
        float2 tv = tab[ts];
        r[u] = make_float2(tv.x, -tv.y);          // e^{-2pi i s/192}
        tw[u] = make_float2(1.f, 0.f);
    }
    float2 acc[4][3];
    #pragma unroll
    for (int u = 0; u < 4; u++)
        #pragma unroll
        for (int k = 0; k < 3; k++) acc[u][k] = make_float2(0.f, 0.f);
    for (int h = 0; h < HH; h++) {
        const float* row = inb + (size_t)h * NWC + wc0;
        float v0 = row[0];
        float v1 = row[256];
        float v2 = row[512];
        #pragma unroll
        for (int u = 0; u < 4; u++) {
            acc[u][0].x += v0 * tw[u].x; acc[u][0].y += v0 * tw[u].y;
            acc[u][1].x += v1 * tw[u].x; acc[u][1].y += v1 * tw[u].y;
            acc[u][2].x += v2 * tw[u].x; acc[u][2].y += v2 * tw[u].y;
            tw[u] = cmul(tw[u], r[u]);
        }
    }
    #pragma unroll
    for (int u = 0; u < 4; u++) {
        int bi = bg*4 + u;
        float2* o = T1 + ((size_t)(b*NBI + bi)) * NWC + wc0;
        o[0] = acc[u][0]; o[256] = acc[u][1]; o[512] = acc[u][2];
    }
}

// K_B: partial forward DFT over W.
// T2[b][bi][bj][c] = sum_w T1[b][bi][w][c] * e^{-2pi i s_j w/192}
__global__ __launch_bounds__(256) void k_dft_w(
        const float2* __restrict__ T1, const float2* __restrict__ tab,
        float2* __restrict__ T2) {
    int bi = blockIdx.x;
    int b  = blockIdx.y;
    int tid = threadIdx.x;
    __shared__ float2 sh[HH][CC];     // 24 KB
    const float2* src = T1 + ((size_t)(b*NBI + bi)) * NWC;
    for (int e = tid; e < NWC; e += 256) sh[e>>4][e&15] = src[e];
    __syncthreads();
    int c = tid >> 4;                 // 0..15
    int bjL = tid & 15;               // 0..15
    float2 tw[5], r[5], acc[5];
    #pragma unroll
    for (int k = 0; k < 5; k++) {
        int bj = bjL + 16*k;
        tw[k] = make_float2(1.f, 0.f);
        acc[k] = make_float2(0.f, 0.f);
        int s = bj - 34;
        int ts = ((s % 192) + 192) % 192;
        float2 tv = tab[ts];
        r[k] = make_float2(tv.x, -tv.y);
    }
    for (int w = 0; w < HH; w++) {
        float2 av = sh[w][c];
        #pragma unroll
        for (int k = 0; k < 5; k++) {
            acc[k].x += av.x*tw[k].x - av.y*tw[k].y;
            acc[k].y += av.x*tw[k].y + av.y*tw[k].x;
            tw[k] = cmul(tw[k], r[k]);
        }
    }
    float2* dst = T2 + ((size_t)((b*NBI + bi)*NBI)) * CC;
    #pragma unroll
    for (int k = 0; k < 5; k++) {
        int bj = bjL + 16*k;
        if (bj < NBI) dst[bj*CC + c] = acc[k];
    }
}

// K_M: per-site 16->32 complex matvec; 8 batches per block share KQ via L1.
__global__ __launch_bounds__(256) void k_mix(
        const float2* __restrict__ T2, const float2* __restrict__ KQ,
        float2* __restrict__ M2) {
    int site = blockIdx.x;            // bi*68 + bj
    int tid = threadIdx.x;
    int b = tid >> 5;                 // 8 groups of 32 lanes
    int g = tid & 31;
    const float2* x  = T2 + ((size_t)b * (NBI*NBI) + site) * CC;
    const float2* kq = KQ + (size_t)site * (CC*FF);
    float2 acc = make_float2(0.f, 0.f);
    #pragma unroll
    for (int cp = 0; cp < CC; cp++) {
        float2 xv = x[cp];
        float2 kv = kq[cp*FF + g];
        acc.x += xv.x*kv.x - xv.y*kv.y;
        acc.y += xv.x*kv.y + xv.y*kv.x;
    }
    M2[((size_t)b * (NBI*NBI) + site) * FF + g] = acc;
}

// K_E2: partial inverse DFT over W.  M3[b][bi][y][g] = sum_bj M2 * e^{+2pi i s_j y/192}
__global__ __launch_bounds__(192) void k_idft_w(
        const float2* __restrict__ M2, const float2* __restrict__ tab,
        float2* __restrict__ M3) {
    int bi = blockIdx.x;
    int b  = blockIdx.y;
    int tid = threadIdx.x;
    __shared__ __align__(16) float2 m2s[NBI][FF];   // 17.4 KB
    const float2* src = M2 + ((size_t)(b*NBI + bi)) * (NBI*FF);
    for (int e = tid; e < NBI*FF; e += 192) m2s[e>>5][e&31] = src[e];
    __syncthreads();
    int ty = tid >> 3;          // 0..23  (8 y per thread)
    int tg = tid & 7;           // 0..7   (4 g per thread)
    int g0 = tg * 4;
    float2 tw[8], rr[8], acc[8][4];
    #pragma unroll
    for (int j = 0; j < 8; j++) {
        int y = ty*8 + j;
        tw[j] = tab[(158 * y) % 192];   // e^{+2pi i (-34) y/192}
        rr[j] = tab[y];                 // e^{+2pi i y/192}
        #pragma unroll
        for (int q = 0; q < 4; q++) acc[j][q] = make_float2(0.f, 0.f);
    }
    for (int bj = 0; bj < NBI; bj++) {
        float4 f0 = *reinterpret_cast<const float4*>(&m2s[bj][g0]);
        float4 f1 = *reinterpret_cast<const float4*>(&m2s[bj][g0+2]);
        float2 m0 = make_float2(f0.x, f0.y);
        float2 m1 = make_float2(f0.z, f0.w);
        float2 m2v = make_float2(f1.x, f1.y);
        float2 m3v = make_float2(f1.z, f1.w);
        #pragma unroll
        for (int j = 0; j < 8; j++) {
            float2 t = tw[j];
            acc[j][0].x += m0.x*t.x - m0.y*t.y;   acc[j][0].y += m0.x*t.y + m0.y*t.x;
            acc[j][1].x += m1.x*t.x - m1.y*t.y;   acc[j][1].y += m1.x*t.y + m1.y*t.x;
            acc[j][2].x += m2v.x*t.x - m2v.y*t.y; acc[j][2].y += m2v.x*t.y + m2v.y*t.x;
            acc[j][3].x += m3v.x*t.x - m3v.y*t.y; acc[j][3].y += m3v.x*t.y + m3v.y*t.x;
            tw[j] = cmul(t, rr[j]);
        }
    }
    float2* dst = M3 + ((size_t)(b*NBI + bi)) * (HH*FF);
    #pragma unroll
    for (int j = 0; j < 8; j++) {
        int y = ty*8 + j;
        float2* o = dst + (size_t)y*FF + g0;
        o[0] = acc[j][0]; o[1] = acc[j][1]; o[2] = acc[j][2]; o[3] = acc[j][3];
    }
}

// K_E3: partial inverse DFT over H, real part, scaled.
// out[b][x][y][g] = SCALE * Re( sum_bi M3[b][bi][y][g] * e^{+2pi i s_i x/192} )
__global__ __launch_bounds__(192) void k_idft_h(
        const float2* __restrict__ M3, const float2* __restrict__ tab,
        float* __restrict__ out) {
    int y = blockIdx.x;
    int b = blockIdx.y;
    int tid = threadIdx.x;
    __shared__ __align__(16) float2 m3s[NBI][FF];
    for (int e = tid; e < NBI*FF; e += 192) {
        int bi = e >> 5, g = e & 31;
        m3s[bi][g] = M3[(((size_t)(b*NBI + bi)) * HH + y) * FF + g];
    }
    __syncthreads();
    int tx = tid >> 3;          // 0..23  (8 x per thread)
    int tg = tid & 7;
    int g0 = tg * 4;
    float2 tw[8], rr[8];
    float acc[8][4];
    #pragma unroll
    for (int j = 0; j < 8; j++) {
        int x = tx*8 + j;
        tw[j] = tab[(158 * x) % 192];
        rr[j] = tab[x];
        #pragma unroll
        for (int q = 0; q < 4; q++) acc[j][q] = 0.f;
    }
    for (int bi = 0; bi < NBI; bi++) {
        float4 f0 = *reinterpret_cast<const float4*>(&m3s[bi][g0]);
        float4 f1 = *reinterpret_cast<const float4*>(&m3s[bi][g0+2]);
        #pragma unroll
        for (int j = 0; j < 8; j++) {
            float2 t = tw[j];
            acc[j][0] += f0.x*t.x - f0.y*t.y;
            acc[j][1] += f0.z*t.x - f0.w*t.y;
            acc[j][2] += f1.x*t.x - f1.y*t.y;
            acc[j][3] += f1.z*t.x - f1.w*t.y;
            tw[j] = cmul(t, rr[j]);
        }
    }
    #pragma unroll
    for (int j = 0; j < 8; j++) {
        int x = tx*8 + j;
        float4 o;
        o.x = acc[j][0]*SCALE; o.y = acc[j][1]*SCALE;
        o.z = acc[j][2]*SCALE; o.w = acc[j][3]*SCALE;
        *reinterpret_cast<float4*>(&out[(((size_t)(b*HH + x)) * WW + y) * FF + g0]) = o;
    }
}

extern "C" void kernel_launch(void* const* d_in, const int* in_sizes, int n_in,
                              void* d_out, int out_size, void* d_ws, size_t ws_size,
                              hipStream_t stream) {
    const float* in = (const float*)d_in[0];
    const float* kr = (const float*)d_in[1];
    const float* ki = (const float*)d_in[2];
    float* out = (float*)d_out;
    char* ws = (char*)d_ws;
    float2* tab = (float2*)(ws + OFF_TAB);
    int* jmin   = (int*)(ws + OFF_JMIN);
    int* rst    = (int*)(ws + OFF_RST);
    float2* KQ  = (float2*)(ws + OFF_KQ);
    float2* T1  = (float2*)(ws + OFF_T1);
    float2* T2  = (float2*)(ws + OFF_T2);
    float2* M2  = (float2*)(ws + OFF_M2);   // aliases T1 (dead by then)
    float2* M3  = (float2*)(ws + OFF_M3);   // overlaps T2 (dead by then)

    k_tables <<<1, 192, 0, stream>>>(tab, jmin, rst);
    k_densify<<<NBI*NBI, 256, 0, stream>>>(kr, ki, tab, jmin, rst, KQ);
    k_dft_h  <<<dim3(17, BB, 4), 256, 0, stream>>>(in, tab, T1);
    k_dft_w  <<<dim3(NBI, BB), 256, 0, stream>>>(T1, tab, T2);
    k_mix    <<<NBI*NBI, 256, 0, stream>>>(T2, KQ, M2);
    k_idft_w <<<dim3(NBI, BB), 192, 0, stream>>>(M2, tab, M3);
    k_idft_h <<<dim3(HH, BB), 192, 0, stream>>>(M3, tab, out);
}

// Round 2
// 282.003 us; speedup vs baseline: 1.1115x; 1.1115x over previous
//
#include <hip/hip_runtime.h>
#include <math.h>

#ifndef M_PI
#define M_PI 3.14159265358979323846
#endif

// Problem constants
#define HH 192
#define WW 192
#define CC 16
#define FF 32
#define BB 8
#define NBI 68        // active frequency box per spatial axis (freqs -34..33)
#define ROW0 62       // first centered (pre-fftshift) row of the mask box
#define MASK_T 4560   // (2i-191)^2 + (2j-191)^2 <= 4560  <=>  d/dmax < 0.25 (exact)
#define NWC (WW*CC)   // 3072
#define SCALE (1.0f/1179648.0f)   // 1/(192*192*32) ifft normalization

// Workspace layout (bytes). Lifetime-packed; peak = 55,152,640 B (same as r0).
#define OFF_TAB  0ull
#define OFF_JMIN 1536ull
#define OFF_RST  1824ull
#define OFF_KQ   4096ull        // 68*68*16*32 float2 = 18,939,904 -> ends 18,944,000
#define OFF_T1   18944000ull    // 2 * 8*68*192*16 float2 = 26,738,688 -> ends 45,682,688
#define OFF_T2   45682688ull    // 8*68*68*16 float2 = 4,734,976 -> ends 50,417,664
#define OFF_M2   18944000ull    // reuses T1 (dead after k_dft_w); 9,469,952 -> ends 28,413,952
#define OFF_M3   28413952ull    // 8*68*192*32 float2 = 26,738,688 -> ends 55,152,640 (T2 dead)
#define T1PART   (BB*NBI*NWC)   // float2 elements per h-partial

__device__ __forceinline__ float2 cmul(float2 a, float2 b) {
    return make_float2(a.x*b.x - a.y*b.y, a.x*b.y + a.y*b.x);
}

// K0: 192-root twiddle table (double-precision build) + mask row tables.
__global__ __launch_bounds__(192) void k_tables(float2* __restrict__ tab,
                                                int* __restrict__ jmin,
                                                int* __restrict__ rstart) {
    int t = threadIdx.x;
    if (t < 192) {
        double th = (2.0 * M_PI / 192.0) * (double)t;
        double s, c;
        sincos(th, &s, &c);
        tab[t] = make_float2((float)c, (float)s);   // e^{+2pi i t/192}
    }
    __shared__ int cnt_s[NBI], jmn_s[NBI];
    if (t < NBI) {
        int ii = ROW0 + t;
        int a = 2*ii - 191;
        int rem = MASK_T - a*a;           // always >= 0 for rows 62..129
        int q = (int)sqrtf((float)rem);
        while ((q+1)*(q+1) <= rem) q++;
        while (q > 0 && q*q > rem) q--;
        jmn_s[t] = (192 - q) >> 1;                        // ceil((191-q)/2)
        cnt_s[t] = ((191 + q) >> 1) - ((192 - q) >> 1) + 1;
    }
    __syncthreads();
    if (t == 0) {
        int acc = 0;
        for (int i = 0; i < NBI; i++) {
            rstart[i] = acc;
            acc += cnt_s[i];
            jmin[i] = jmn_s[i];
        }
        // acc == 3576 (= N_ACTIVE / (C*F)), verified analytically.
    }
}

// K1: scatter the flat weights into the 68x68 box AND fold in the C-forward-DFT
// and F-inverse-DFT:  KQ[c',g] = sum_{c,f} e^{-2pi i c c'/16} K[c,f] e^{+2pi i f g/32}
__global__ __launch_bounds__(256) void k_densify(
        const float* __restrict__ kr, const float* __restrict__ ki,
        const float2* __restrict__ tab, const int* __restrict__ jmin,
        const int* __restrict__ rstart, float2* __restrict__ KQ) {
    int blk = blockIdx.x;                 // bi*68 + bj
    int bi = blk / NBI, bj = blk - bi*NBI;
    int tid = threadIdx.x;
    float2* KQo = KQ + (size_t)blk * (CC*FF);
    int a = 2*(ROW0+bi) - 191;
    int bc = 2*(ROW0+bj) - 191;
    bool masked = (a*a + bc*bc) <= MASK_T;   // block-uniform
    if (!masked) {
        for (int e = tid; e < CC*FF; e += 256) KQo[e] = make_float2(0.f, 0.f);
        return;
    }
    __shared__ float2 Kc[CC][FF+1];
    __shared__ float2 Kt[CC][FF+1];
    __shared__ float2 tl[192];
    for (int e = tid; e < 192; e += 256) tl[e] = tab[e];
    int rank = rstart[bi] + ((ROW0+bj) - jmin[bi]);
    size_t base = (size_t)rank * (CC*FF);
    for (int e = tid; e < CC*FF; e += 256)
        Kc[e>>5][e&31] = make_float2(kr[base+e], ki[base+e]);
    __syncthreads();
    for (int e = tid; e < CC*FF; e += 256) {      // Kt[cp][f] = DFT16_c
        int cp = e >> 5, f = e & 31;
        float2 acc = make_float2(0.f, 0.f);
        #pragma unroll
        for (int c = 0; c < CC; c++) {
            int tt = (12*c*cp) % 192;             // 2pi/16 = 2pi*12/192
            float2 w = tl[tt];
            float2 v = Kc[c][f];
            acc.x += v.x*w.x + v.y*w.y;           // v * conj(w)
            acc.y += v.y*w.x - v.x*w.y;
        }
        Kt[cp][f] = acc;
    }
    __syncthreads();
    for (int e = tid; e < CC*FF; e += 256) {      // KQ[cp][g] = iDFT32_f
        int cp = e >> 5, g = e & 31;
        float2 acc = make_float2(0.f, 0.f);
        #pragma unroll
        for (int f = 0; f < FF; f++) {
            int tt = (6*f*g) % 192;               // 2pi/32 = 2pi*6/192
            float2 w = tl[tt];
            float2 v = Kt[cp][f];
            acc.x += v.x*w.x - v.y*w.y;           // v * w
            acc.y += v.x*w.y + v.y*w.x;
        }
        KQo[cp*FF + g] = acc;
    }
}

// K_A: partial forward DFT over H at the 68 active freqs (rotation twiddles).
// Split the h-reduction in 2 partials for occupancy; k_dft_w sums them.
// T1[part][b][bi][w][c] = sum_{h in part} in[b][h][w][c] * e^{-2pi i s_i h/192}
__global__ __launch_bounds__(256) void k_dft_h(
        const float* __restrict__ in, const float2* __restrict__ tab,
        float2* __restrict__ T1) {
    int bg = blockIdx.x;          // 0..16, 4 bi each
    int b  = blockIdx.y;
    int zc = blockIdx.z;          // (wc quarter)*2 + h-part
    int z  = zc >> 1;
    int part = zc & 1;
    int h0 = part * (HH/2);
    int tid = threadIdx.x;
    const float* inb = in + (size_t)b * HH * NWC;
    int wc0 = z * 768 + tid;
    float2 tw[4], r[4];
    #pragma unroll
    for (int u = 0; u < 4; u++) {
        int s = bg*4 + u - 34;
        int ts = ((s % 192) + 192) % 192;
        float2 tv = tab[ts];
        r[u] = make_float2(tv.x, -tv.y);          // e^{-2pi i s/192}
        int ts0 = (((s*h0) % 192) + 192) % 192;
        float2 t0 = tab[ts0];
        tw[u] = make_float2(t0.x, -t0.y);         // e^{-2pi i s h0/192}
    }
    float2 acc[4][3];
    #pragma unroll
    for (int u = 0; u < 4; u++)
        #pragma unroll
        for (int k = 0; k < 3; k++) acc[u][k] = make_float2(0.f, 0.f);
    for (int h = h0; h < h0 + HH/2; h++) {
        const float* row = inb + (size_t)h * NWC + wc0;
        float v0 = row[0];
        float v1 = row[256];
        float v2 = row[512];
        #pragma unroll
        for (int u = 0; u < 4; u++) {
            acc[u][0].x += v0 * tw[u].x; acc[u][0].y += v0 * tw[u].y;
            acc[u][1].x += v1 * tw[u].x; acc[u][1].y += v1 * tw[u].y;
            acc[u][2].x += v2 * tw[u].x; acc[u][2].y += v2 * tw[u].y;
            tw[u] = cmul(tw[u], r[u]);
        }
    }
    #pragma unroll
    for (int u = 0; u < 4; u++) {
        int bi = bg*4 + u;
        float2* o = T1 + (size_t)part * T1PART + ((size_t)(b*NBI + bi)) * NWC + wc0;
        o[0] = acc[u][0]; o[256] = acc[u][1]; o[512] = acc[u][2];
    }
}

// K_B: partial forward DFT over W (sums the two h-partials at LDS fill).
// T2[b][bi][bj][c] = sum_w T1[b][bi][w][c] * e^{-2pi i s_j w/192}
__global__ __launch_bounds__(256) void k_dft_w(
        const float2* __restrict__ T1, const float2* __restrict__ tab,
        float2* __restrict__ T2) {
    int bi = blockIdx.x;
    int b  = blockIdx.y;
    int half = blockIdx.z;            // bj half: 0 -> 0..33, 1 -> 34..67
    int tid = threadIdx.x;
    __shared__ float2 sh[HH][CC];     // 24 KB
    const float2* src0 = T1 + ((size_t)(b*NBI + bi)) * NWC;
    const float2* src1 = src0 + T1PART;
    for (int e = tid; e < NWC; e += 256) {
        float2 a0 = src0[e], a1 = src1[e];
        sh[e>>4][e&15] = make_float2(a0.x + a1.x, a0.y + a1.y);
    }
    __syncthreads();
    int c = tid >> 4;                 // 0..15
    int bjL = tid & 15;               // 0..15
    float2 tw[3], r[3], acc[3];
    #pragma unroll
    for (int k = 0; k < 3; k++) {
        int bj = half*34 + bjL + 16*k;
        tw[k] = make_float2(1.f, 0.f);
        acc[k] = make_float2(0.f, 0.f);
        int s = (bj < NBI ? bj : 0) - 34;
        int ts = ((s % 192) + 192) % 192;
        float2 tv = tab[ts];
        r[k] = make_float2(tv.x, -tv.y);
    }
    for (int w = 0; w < HH; w++) {
        float2 av = sh[w][c];
        #pragma unroll
        for (int k = 0; k < 3; k++) {
            acc[k].x += av.x*tw[k].x - av.y*tw[k].y;
            acc[k].y += av.x*tw[k].y + av.y*tw[k].x;
            tw[k] = cmul(tw[k], r[k]);
        }
    }
    float2* dst = T2 + ((size_t)((b*NBI + bi)*NBI)) * CC;
    #pragma unroll
    for (int k = 0; k < 3; k++) {
        int bj = half*34 + bjL + 16*k;
        if (bjL + 16*k < 34) dst[bj*CC + c] = acc[k];
    }
}

// K_M: per-site 16->32 complex matvec; 8 batches per block share KQ via L1.
__global__ __launch_bounds__(256) void k_mix(
        const float2* __restrict__ T2, const float2* __restrict__ KQ,
        float2* __restrict__ M2) {
    int site = blockIdx.x;            // bi*68 + bj
    int tid = threadIdx.x;
    int b = tid >> 5;                 // 8 groups of 32 lanes
    int g = tid & 31;
    const float2* x  = T2 + ((size_t)b * (NBI*NBI) + site) * CC;
    const float2* kq = KQ + (size_t)site * (CC*FF);
    float2 acc = make_float2(0.f, 0.f);
    #pragma unroll
    for (int cp = 0; cp < CC; cp++) {
        float2 xv = x[cp];
        float2 kv = kq[cp*FF + g];
        acc.x += xv.x*kv.x - xv.y*kv.y;
        acc.y += xv.x*kv.y + xv.y*kv.x;
    }
    M2[((size_t)b * (NBI*NBI) + site) * FF + g] = acc;
}

// K_E2: partial inverse DFT over W, y split 4-ways for occupancy.
// M3[b][bi][y][g] = sum_bj M2 * e^{+2pi i s_j y/192}
__global__ __launch_bounds__(192) void k_idft_w(
        const float2* __restrict__ M2, const float2* __restrict__ tab,
        float2* __restrict__ M3) {
    int bi = blockIdx.x;
    int b  = blockIdx.y;
    int y0 = blockIdx.z * 48;     // y chunk
    int tid = threadIdx.x;
    __shared__ __align__(16) float2 m2s[NBI][FF];   // 17.4 KB
    const float2* src = M2 + ((size_t)(b*NBI + bi)) * (NBI*FF);
    for (int e = tid; e < NBI*FF; e += 192) m2s[e>>5][e&31] = src[e];
    __syncthreads();
    int ty = tid >> 3;          // 0..23  (2 y per thread)
    int tg = tid & 7;           // 0..7   (4 g per thread)
    int g0 = tg * 4;
    float2 tw[2], rr[2], acc[2][4];
    #pragma unroll
    for (int j = 0; j < 2; j++) {
        int y = y0 + ty*2 + j;
        tw[j] = tab[(158 * y) % 192];   // e^{+2pi i (-34) y/192}
        rr[j] = tab[y];                 // e^{+2pi i y/192}
        #pragma unroll
        for (int q = 0; q < 4; q++) acc[j][q] = make_float2(0.f, 0.f);
    }
    for (int bj = 0; bj < NBI; bj++) {
        float4 f0 = *reinterpret_cast<const float4*>(&m2s[bj][g0]);
        float4 f1 = *reinterpret_cast<const float4*>(&m2s[bj][g0+2]);
        float2 m0 = make_float2(f0.x, f0.y);
        float2 m1 = make_float2(f0.z, f0.w);
        float2 m2v = make_float2(f1.x, f1.y);
        float2 m3v = make_float2(f1.z, f1.w);
        #pragma unroll
        for (int j = 0; j < 2; j++) {
            float2 t = tw[j];
            acc[j][0].x += m0.x*t.x - m0.y*t.y;   acc[j][0].y += m0.x*t.y + m0.y*t.x;
            acc[j][1].x += m1.x*t.x - m1.y*t.y;   acc[j][1].y += m1.x*t.y + m1.y*t.x;
            acc[j][2].x += m2v.x*t.x - m2v.y*t.y; acc[j][2].y += m2v.x*t.y + m2v.y*t.x;
            acc[j][3].x += m3v.x*t.x - m3v.y*t.y; acc[j][3].y += m3v.x*t.y + m3v.y*t.x;
            tw[j] = cmul(t, rr[j]);
        }
    }
    float2* dst = M3 + ((size_t)(b*NBI + bi)) * (HH*FF);
    #pragma unroll
    for (int j = 0; j < 2; j++) {
        int y = y0 + ty*2 + j;
        float2* o = dst + (size_t)y*FF + g0;
        o[0] = acc[j][0]; o[1] = acc[j][1]; o[2] = acc[j][2]; o[3] = acc[j][3];
    }
}

// K_E3: partial inverse DFT over H, real part, scaled; x split 2-ways.
// out[b][x][y][g] = SCALE * Re( sum_bi M3[b][bi][y][g] * e^{+2pi i s_i x/192} )
__global__ __launch_bounds__(192) void k_idft_h(
        const float2* __restrict__ M3, const float2* __restrict__ tab,
        float* __restrict__ out) {
    int y = blockIdx.x;
    int b = blockIdx.y;
    int x0 = blockIdx.z * 96;
    int tid = threadIdx.x;
    __shared__ __align__(16) float2 m3s[NBI][FF];
    for (int e = tid; e < NBI*FF; e += 192) {
        int bi = e >> 5, g = e & 31;
        m3s[bi][g] = M3[(((size_t)(b*NBI + bi)) * HH + y) * FF + g];
    }
    __syncthreads();
    int tx = tid >> 3;          // 0..23  (4 x per thread)
    int tg = tid & 7;
    int g0 = tg * 4;
    float2 tw[4], rr[4];
    float acc[4][4];
    #pragma unroll
    for (int j = 0; j < 4; j++) {
        int x = x0 + tx*4 + j;
        tw[j] = tab[(158 * x) % 192];
        rr[j] = tab[x];
        #pragma unroll
        for (int q = 0; q < 4; q++) acc[j][q] = 0.f;
    }
    for (int bi = 0; bi < NBI; bi++) {
        float4 f0 = *reinterpret_cast<const float4*>(&m3s[bi][g0]);
        float4 f1 = *reinterpret_cast<const float4*>(&m3s[bi][g0+2]);
        #pragma unroll
        for (int j = 0; j < 4; j++) {
            float2 t = tw[j];
            acc[j][0] += f0.x*t.x - f0.y*t.y;
            acc[j][1] += f0.z*t.x - f0.w*t.y;
            acc[j][2] += f1.x*t.x - f1.y*t.y;
            acc[j][3] += f1.z*t.x - f1.w*t.y;
            tw[j] = cmul(t, rr[j]);
        }
    }
    #pragma unroll
    for (int j = 0; j < 4; j++) {
        int x = x0 + tx*4 + j;
        float4 o;
        o.x = acc[j][0]*SCALE; o.y = acc[j][1]*SCALE;
        o.z = acc[j][2]*SCALE; o.w = acc[j][3]*SCALE;
        *reinterpret_cast<float4*>(&out[(((size_t)(b*HH + x)) * WW + y) * FF + g0]) = o;
    }
}

extern "C" void kernel_launch(void* const* d_in, const int* in_sizes, int n_in,
                              void* d_out, int out_size, void* d_ws, size_t ws_size,
                              hipStream_t stream) {
    const float* in = (const float*)d_in[0];
    const float* kr = (const float*)d_in[1];
    const float* ki = (const float*)d_in[2];
    float* out = (float*)d_out;
    char* ws = (char*)d_ws;
    float2* tab = (float2*)(ws + OFF_TAB);
    int* jmin   = (int*)(ws + OFF_JMIN);
    int* rst    = (int*)(ws + OFF_RST);
    float2* KQ  = (float2*)(ws + OFF_KQ);
    float2* T1  = (float2*)(ws + OFF_T1);
    float2* T2  = (float2*)(ws + OFF_T2);
    float2* M2  = (float2*)(ws + OFF_M2);   // aliases T1 (dead by then)
    float2* M3  = (float2*)(ws + OFF_M3);   // overlaps T2 (dead by then)

    k_tables <<<1, 192, 0, stream>>>(tab, jmin, rst);
    k_densify<<<NBI*NBI, 256, 0, stream>>>(kr, ki, tab, jmin, rst, KQ);
    k_dft_h  <<<dim3(17, BB, 8), 256, 0, stream>>>(in, tab, T1);
    k_dft_w  <<<dim3(NBI, BB, 2), 256, 0, stream>>>(T1, tab, T2);
    k_mix    <<<NBI*NBI, 256, 0, stream>>>(T2, KQ, M2);
    k_idft_w <<<dim3(NBI, BB, 4), 192, 0, stream>>>(M2, tab, M3);
    k_idft_h <<<dim3(HH, BB, 2), 192, 0, stream>>>(M3, tab, out);
}

// Round 3
// 209.851 us; speedup vs baseline: 1.4937x; 1.3438x over previous
//
#include <hip/hip_runtime.h>
#include <math.h>

#ifndef M_PI
#define M_PI 3.14159265358979323846
#endif

// Problem constants
#define HH 192
#define WW 192
#define CC 16
#define FF 32
#define BB 8
#define NBI 68        // active frequency box per spatial axis (freqs -34..33)
#define NROW 35       // computed H-spectrum rows: s = 0..34 (rest by conj symmetry)
#define NCOL 69       // computed W-spectrum cols: sj = -34..34 (col = sj+34)
#define ROW0 62       // first centered (pre-fftshift) row of the mask box
#define MASK_T 4560   // (2i-191)^2 + (2j-191)^2 <= 4560  <=>  d/dmax < 0.25 (exact)
#define NWC (WW*CC)   // 3072
#define NPART 4       // h-reduction partials in k_dft_h
#define SCALE (1.0f/1179648.0f)   // 1/(192*192*32) ifft normalization

// Workspace layout (bytes). Lifetime-packed; peak = 55,152,640 B (same as r1/r2).
#define OFF_TAB  0ull
#define OFF_JMIN 1536ull
#define OFF_RST  1824ull
#define OFF_KQ   4096ull        // 68*68*16*32 float2 = 18,939,904 -> ends 18,944,000
#define OFF_T1   18944000ull    // 4 * 8*35*3072 float2 = 27,525,120 -> ends 46,469,120
#define OFF_T2   46469120ull    // 8*35*69*16 float2 = 2,472,960 -> ends 48,942,080
#define OFF_M2   18944000ull    // reuses T1 (dead after k_dft_w); 9,469,952 -> ends 28,413,952
#define OFF_M3   28413952ull    // 8*68*192*32 float2 = 26,738,688 -> ends 55,152,640 (T1/T2 dead)
#define T1PART   (BB*NROW*NWC)  // float2 elements per h-partial

__device__ __forceinline__ float2 cmul(float2 a, float2 b) {
    return make_float2(a.x*b.x - a.y*b.y, a.x*b.y + a.y*b.x);
}

// K0: 192-root twiddle table (double-precision build) + mask row tables.
__global__ __launch_bounds__(192) void k_tables(float2* __restrict__ tab,
                                                int* __restrict__ jmin,
                                                int* __restrict__ rstart) {
    int t = threadIdx.x;
    if (t < 192) {
        double th = (2.0 * M_PI / 192.0) * (double)t;
        double s, c;
        sincos(th, &s, &c);
        tab[t] = make_float2((float)c, (float)s);   // e^{+2pi i t/192}
    }
    __shared__ int cnt_s[NBI], jmn_s[NBI];
    if (t < NBI) {
        int ii = ROW0 + t;
        int a = 2*ii - 191;
        int rem = MASK_T - a*a;           // always >= 0 for rows 62..129
        int q = (int)sqrtf((float)rem);
        while ((q+1)*(q+1) <= rem) q++;
        while (q > 0 && q*q > rem) q--;
        jmn_s[t] = (192 - q) >> 1;                        // ceil((191-q)/2)
        cnt_s[t] = ((191 + q) >> 1) - ((192 - q) >> 1) + 1;
    }
    __syncthreads();
    if (t == 0) {
        int acc = 0;
        for (int i = 0; i < NBI; i++) {
            rstart[i] = acc;
            acc += cnt_s[i];
            jmin[i] = jmn_s[i];
        }
        // acc == 3576 (= N_ACTIVE / (C*F)), verified analytically.
    }
}

// K1: scatter the flat weights into the 68x68 box AND fold in the C-forward-DFT
// and F-inverse-DFT:  KQ[c,g] = sum_{sc,f} e^{-2pi i c sc/16} K[sc,f] e^{+2pi i f g/32}
__global__ __launch_bounds__(256) void k_densify(
        const float* __restrict__ kr, const float* __restrict__ ki,
        const float2* __restrict__ tab, const int* __restrict__ jmin,
        const int* __restrict__ rstart, float2* __restrict__ KQ) {
    int blk = blockIdx.x;                 // bi*68 + bj
    int bi = blk / NBI, bj = blk - bi*NBI;
    int tid = threadIdx.x;
    float2* KQo = KQ + (size_t)blk * (CC*FF);
    int a = 2*(ROW0+bi) - 191;
    int bc = 2*(ROW0+bj) - 191;
    bool masked = (a*a + bc*bc) <= MASK_T;   // block-uniform
    if (!masked) {
        for (int e = tid; e < CC*FF; e += 256) KQo[e] = make_float2(0.f, 0.f);
        return;
    }
    __shared__ float2 Kc[CC][FF+1];
    __shared__ float2 Kt[CC][FF+1];
    __shared__ float2 tl[192];
    for (int e = tid; e < 192; e += 256) tl[e] = tab[e];
    int rank = rstart[bi] + ((ROW0+bj) - jmin[bi]);
    size_t base = (size_t)rank * (CC*FF);
    for (int e = tid; e < CC*FF; e += 256)
        Kc[e>>5][e&31] = make_float2(kr[base+e], ki[base+e]);
    __syncthreads();
    for (int e = tid; e < CC*FF; e += 256) {      // Kt[cp][f] = DFT16_c
        int cp = e >> 5, f = e & 31;
        float2 acc = make_float2(0.f, 0.f);
        #pragma unroll
        for (int c = 0; c < CC; c++) {
            int tt = (12*c*cp) % 192;             // 2pi/16 = 2pi*12/192
            float2 w = tl[tt];
            float2 v = Kc[c][f];
            acc.x += v.x*w.x + v.y*w.y;           // v * conj(w)
            acc.y += v.y*w.x - v.x*w.y;
        }
        Kt[cp][f] = acc;
    }
    __syncthreads();
    for (int e = tid; e < CC*FF; e += 256) {      // KQ[cp][g] = iDFT32_f
        int cp = e >> 5, g = e & 31;
        float2 acc = make_float2(0.f, 0.f);
        #pragma unroll
        for (int f = 0; f < FF; f++) {
            int tt = (6*f*g) % 192;               // 2pi/32 = 2pi*6/192
            float2 w = tl[tt];
            float2 v = Kt[cp][f];
            acc.x += v.x*w.x - v.y*w.y;           // v * w
            acc.y += v.x*w.y + v.y*w.x;
        }
        KQo[cp*FF + g] = acc;
    }
}

// K_A: partial forward DFT over H at s = 0..34 only (input real -> Hermitian).
// T1[part][b][row][w][c] = sum_{h in part} in[b][h][w][c] * e^{-2pi i s h/192}, s=row
__global__ __launch_bounds__(256) void k_dft_h(
        const float* __restrict__ in, const float2* __restrict__ tab,
        float2* __restrict__ T1) {
    int bg = blockIdx.x;          // 0..8, 4 rows each (row 35 padded off)
    int b  = blockIdx.y;
    int zc = blockIdx.z;          // quarter*NPART + part
    int z  = zc / NPART;
    int part = zc - z*NPART;
    int h0 = part * (HH/NPART);
    int tid = threadIdx.x;
    const float* inb = in + (size_t)b * HH * NWC;
    int wc0 = z * 768 + tid;
    float2 tw[4], r[4];
    #pragma unroll
    for (int u = 0; u < 4; u++) {
        int row = bg*4 + u;
        int s = row < NROW ? row : 0;
        float2 tv = tab[s];
        r[u] = make_float2(tv.x, -tv.y);          // e^{-2pi i s/192}
        float2 t0 = tab[(s*h0) % 192];
        tw[u] = make_float2(t0.x, -t0.y);         // e^{-2pi i s h0/192}
    }
    float2 acc[4][3];
    #pragma unroll
    for (int u = 0; u < 4; u++)
        #pragma unroll
        for (int k = 0; k < 3; k++) acc[u][k] = make_float2(0.f, 0.f);
    for (int h = h0; h < h0 + HH/NPART; h++) {
        const float* row = inb + (size_t)h * NWC + wc0;
        float v0 = row[0];
        float v1 = row[256];
        float v2 = row[512];
        #pragma unroll
        for (int u = 0; u < 4; u++) {
            acc[u][0].x += v0 * tw[u].x; acc[u][0].y += v0 * tw[u].y;
            acc[u][1].x += v1 * tw[u].x; acc[u][1].y += v1 * tw[u].y;
            acc[u][2].x += v2 * tw[u].x; acc[u][2].y += v2 * tw[u].y;
            tw[u] = cmul(tw[u], r[u]);
        }
    }
    #pragma unroll
    for (int u = 0; u < 4; u++) {
        int row = bg*4 + u;
        if (row < NROW) {
            float2* o = T1 + (size_t)part * T1PART + ((size_t)(b*NROW + row)) * NWC + wc0;
            o[0] = acc[u][0]; o[256] = acc[u][1]; o[512] = acc[u][2];
        }
    }
}

// K_B: partial forward DFT over W for the 35 computed rows, 69 cols (sj=-34..34).
// T2[b][row][col][c] = sum_w T1sum[b][row][w][c] * e^{-2pi i (col-34) w/192}
__global__ __launch_bounds__(256) void k_dft_w(
        const float2* __restrict__ T1, const float2* __restrict__ tab,
        float2* __restrict__ T2) {
    int row = blockIdx.x;             // 0..34
    int b   = blockIdx.y;
    int half = blockIdx.z;            // 0: cols 0..34, 1: cols 35..68
    int tid = threadIdx.x;
    __shared__ float2 sh[HH][CC];     // 24 KB
    const float2* src = T1 + ((size_t)(b*NROW + row)) * NWC;
    for (int e = tid; e < NWC; e += 256) {
        float2 a0 = src[e];
        float2 a1 = src[e + T1PART];
        float2 a2 = src[e + 2*T1PART];
        float2 a3 = src[e + 3*T1PART];
        sh[e>>4][e&15] = make_float2(a0.x+a1.x+a2.x+a3.x, a0.y+a1.y+a2.y+a3.y);
    }
    __syncthreads();
    int c = tid >> 4;                 // 0..15
    int bjL = tid & 15;               // 0..15
    float2 tw[3], r[3], acc[3];
    #pragma unroll
    for (int k = 0; k < 3; k++) {
        int off = bjL + 16*k;
        int col = half*35 + off;
        bool valid = (half == 0) ? (off < 35) : (off < 34);
        int sj = (valid ? col : 34) - 34;
        tw[k] = make_float2(1.f, 0.f);
        acc[k] = make_float2(0.f, 0.f);
        int ts = ((sj % 192) + 192) % 192;
        float2 tv = tab[ts];
        r[k] = make_float2(tv.x, -tv.y);
    }
    for (int w = 0; w < HH; w++) {
        float2 av = sh[w][c];
        #pragma unroll
        for (int k = 0; k < 3; k++) {
            acc[k].x += av.x*tw[k].x - av.y*tw[k].y;
            acc[k].y += av.x*tw[k].y + av.y*tw[k].x;
            tw[k] = cmul(tw[k], r[k]);
        }
    }
    float2* dst = T2 + ((size_t)((b*NROW + row)*NCOL)) * CC;
    #pragma unroll
    for (int k = 0; k < 3; k++) {
        int off = bjL + 16*k;
        int col = half*35 + off;
        bool valid = (half == 0) ? (off < 35) : (off < 34);
        if (valid) dst[col*CC + c] = acc[k];
    }
}

// K_M: per-site 16->32 complex matvec; negative-s rows read the conj mirror.
__global__ __launch_bounds__(256) void k_mix(
        const float2* __restrict__ T2, const float2* __restrict__ KQ,
        float2* __restrict__ M2) {
    int site = blockIdx.x;            // bi*68 + bj
    int bi = site / NBI, bj = site - bi*NBI;
    int tid = threadIdx.x;
    int b = tid >> 5;                 // 8 groups of 32 lanes
    int g = tid & 31;
    int row, col;
    bool cj;
    if (bi >= 34) { row = bi - 34; col = bj;      cj = false; }
    else          { row = 34 - bi; col = 68 - bj; cj = true;  }
    const float2* x  = T2 + ((size_t)(b*NROW + row) * NCOL + col) * CC;
    const float2* kq = KQ + (size_t)site * (CC*FF);
    float sgn = cj ? -1.f : 1.f;
    float2 acc = make_float2(0.f, 0.f);
    #pragma unroll
    for (int cp = 0; cp < CC; cp++) {
        float2 xv = x[cp];
        xv.y *= sgn;
        float2 kv = kq[cp*FF + g];
        acc.x += xv.x*kv.x - xv.y*kv.y;
        acc.y += xv.x*kv.y + xv.y*kv.x;
    }
    M2[((size_t)b * (NBI*NBI) + site) * FF + g] = acc;
}

// K_E2: partial inverse DFT over W, y split 4-ways for occupancy.
// M3[b][bi][y][g] = sum_bj M2 * e^{+2pi i s_j y/192}
__global__ __launch_bounds__(192) void k_idft_w(
        const float2* __restrict__ M2, const float2* __restrict__ tab,
        float2* __restrict__ M3) {
    int bi = blockIdx.x;
    int b  = blockIdx.y;
    int y0 = blockIdx.z * 48;     // y chunk
    int tid = threadIdx.x;
    __shared__ __align__(16) float2 m2s[NBI][FF];   // 17.4 KB
    const float2* src = M2 + ((size_t)(b*NBI + bi)) * (NBI*FF);
    for (int e = tid; e < NBI*FF; e += 192) m2s[e>>5][e&31] = src[e];
    __syncthreads();
    int ty = tid >> 3;          // 0..23  (2 y per thread)
    int tg = tid & 7;           // 0..7   (4 g per thread)
    int g0 = tg * 4;
    float2 tw[2], rr[2], acc[2][4];
    #pragma unroll
    for (int j = 0; j < 2; j++) {
        int y = y0 + ty*2 + j;
        tw[j] = tab[(158 * y) % 192];   // e^{+2pi i (-34) y/192}
        rr[j] = tab[y];                 // e^{+2pi i y/192}
        #pragma unroll
        for (int q = 0; q < 4; q++) acc[j][q] = make_float2(0.f, 0.f);
    }
    for (int bj = 0; bj < NBI; bj++) {
        float4 f0 = *reinterpret_cast<const float4*>(&m2s[bj][g0]);
        float4 f1 = *reinterpret_cast<const float4*>(&m2s[bj][g0+2]);
        float2 m0 = make_float2(f0.x, f0.y);
        float2 m1 = make_float2(f0.z, f0.w);
        float2 m2v = make_float2(f1.x, f1.y);
        float2 m3v = make_float2(f1.z, f1.w);
        #pragma unroll
        for (int j = 0; j < 2; j++) {
            float2 t = tw[j];
            acc[j][0].x += m0.x*t.x - m0.y*t.y;   acc[j][0].y += m0.x*t.y + m0.y*t.x;
            acc[j][1].x += m1.x*t.x - m1.y*t.y;   acc[j][1].y += m1.x*t.y + m1.y*t.x;
            acc[j][2].x += m2v.x*t.x - m2v.y*t.y; acc[j][2].y += m2v.x*t.y + m2v.y*t.x;
            acc[j][3].x += m3v.x*t.x - m3v.y*t.y; acc[j][3].y += m3v.x*t.y + m3v.y*t.x;
            tw[j] = cmul(t, rr[j]);
        }
    }
    float2* dst = M3 + ((size_t)(b*NBI + bi)) * (HH*FF);
    #pragma unroll
    for (int j = 0; j < 2; j++) {
        int y = y0 + ty*2 + j;
        float2* o = dst + (size_t)y*FF + g0;
        o[0] = acc[j][0]; o[1] = acc[j][1]; o[2] = acc[j][2]; o[3] = acc[j][3];
    }
}

// K_E3: partial inverse DFT over H keeping Re only, via (s,-s) Hermitian pairing:
// out += A_p cos(2pi p x/192) - B_p sin(2pi p x/192), p = 0..34.
// p=0:  A = M3[s=0].x, B = 0 (tw.y=0 at p=0 anyway)
// p=34: A = M3[s=-34].x, B = -M3[s=-34].y
// else: A = M3[s=p].x + M3[s=-p].x, B = M3[s=p].y - M3[s=-p].y
__global__ __launch_bounds__(192) void k_idft_h(
        const float2* __restrict__ M3, const float2* __restrict__ tab,
        float* __restrict__ out) {
    int y = blockIdx.x;
    int b = blockIdx.y;
    int x0 = blockIdx.z * 96;
    int tid = threadIdx.x;
    __shared__ __align__(16) float2 comb[NROW][FF];   // (A,B) per pair, 8.96 KB
    for (int e = tid; e < NROW*FF; e += 192) {
        int p = e >> 5, g = e & 31;
        float A, Bv;
        if (p == 0) {
            float2 v = M3[(((size_t)(b*NBI + 34)) * HH + y) * FF + g];
            A = v.x; Bv = 0.f;
        } else if (p == 34) {
            float2 v = M3[(((size_t)(b*NBI + 0)) * HH + y) * FF + g];
            A = v.x; Bv = -v.y;
        } else {
            float2 vp = M3[(((size_t)(b*NBI + 34 + p)) * HH + y) * FF + g];
            float2 vm = M3[(((size_t)(b*NBI + 34 - p)) * HH + y) * FF + g];
            A = vp.x + vm.x; Bv = vp.y - vm.y;
        }
        comb[p][g] = make_float2(A, Bv);
    }
    __syncthreads();
    int tx = tid >> 3;          // 0..23  (4 x per thread)
    int tg = tid & 7;
    int g0 = tg * 4;
    float2 tw[4], rr[4];
    float acc[4][4];
    #pragma unroll
    for (int j = 0; j < 4; j++) {
        int x = x0 + tx*4 + j;
        tw[j] = make_float2(1.f, 0.f);   // angle p=0
        rr[j] = tab[x];                  // e^{+2pi i x/192} per p step
        #pragma unroll
        for (int q = 0; q < 4; q++) acc[j][q] = 0.f;
    }
    for (int p = 0; p < NROW; p++) {
        float4 f0 = *reinterpret_cast<const float4*>(&comb[p][g0]);     // A0,B0,A1,B1
        float4 f1 = *reinterpret_cast<const float4*>(&comb[p][g0+2]);   // A2,B2,A3,B3
        #pragma unroll
        for (int j = 0; j < 4; j++) {
            float2 t = tw[j];
            acc[j][0] += f0.x*t.x - f0.y*t.y;
            acc[j][1] += f0.z*t.x - f0.w*t.y;
            acc[j][2] += f1.x*t.x - f1.y*t.y;
            acc[j][3] += f1.z*t.x - f1.w*t.y;
            tw[j] = cmul(t, rr[j]);
        }
    }
    #pragma unroll
    for (int j = 0; j < 4; j++) {
        int x = x0 + tx*4 + j;
        float4 o;
        o.x = acc[j][0]*SCALE; o.y = acc[j][1]*SCALE;
        o.z = acc[j][2]*SCALE; o.w = acc[j][3]*SCALE;
        *reinterpret_cast<float4*>(&out[(((size_t)(b*HH + x)) * WW + y) * FF + g0]) = o;
    }
}

extern "C" void kernel_launch(void* const* d_in, const int* in_sizes, int n_in,
                              void* d_out, int out_size, void* d_ws, size_t ws_size,
                              hipStream_t stream) {
    const float* in = (const float*)d_in[0];
    const float* kr = (const float*)d_in[1];
    const float* ki = (const float*)d_in[2];
    float* out = (float*)d_out;
    char* ws = (char*)d_ws;
    float2* tab = (float2*)(ws + OFF_TAB);
    int* jmin   = (int*)(ws + OFF_JMIN);
    int* rst    = (int*)(ws + OFF_RST);
    float2* KQ  = (float2*)(ws + OFF_KQ);
    float2* T1  = (float2*)(ws + OFF_T1);
    float2* T2  = (float2*)(ws + OFF_T2);
    float2* M2  = (float2*)(ws + OFF_M2);   // aliases T1 (dead by then)
    float2* M3  = (float2*)(ws + OFF_M3);   // overlaps T1 tail / T2 (dead by then)

    k_tables <<<1, 192, 0, stream>>>(tab, jmin, rst);
    k_densify<<<NBI*NBI, 256, 0, stream>>>(kr, ki, tab, jmin, rst, KQ);
    k_dft_h  <<<dim3(9, BB, 4*NPART), 256, 0, stream>>>(in, tab, T1);
    k_dft_w  <<<dim3(NROW, BB, 2), 256, 0, stream>>>(T1, tab, T2);
    k_mix    <<<NBI*NBI, 256, 0, stream>>>(T2, KQ, M2);
    k_idft_w <<<dim3(NBI, BB, 4), 192, 0, stream>>>(M2, tab, M3);
    k_idft_h <<<dim3(HH, BB, 2), 192, 0, stream>>>(M3, tab, out);
}